// Round 7
// baseline (1309.007 us; speedup 1.0000x reference)
//
#include <hip/hip_runtime.h>
#include <math.h>

#define BB 8
#define NN 4096
#define CC 256
#define DD 64
#define MM 1024
#define KNB 16
#define OC 259

typedef unsigned long long ull;

// ---------------------------------------------------------------------------
// PHASE 1: blocks 0-7 FPS (one per batch) | 8 prep | 9-24 W12 | 25-2072
// transpose fm->(B,N,C). Roles are block-uniform; fps dominates (~500us),
// the other 2065 blocks (~50us of work) run concurrently on the idle CUs.
__global__ __launch_bounds__(256) void phase1(
    const float* __restrict__ verts, const float* __restrict__ fm,
    const float* __restrict__ pw1, const float* __restrict__ pb1,
    const float* __restrict__ g1, const float* __restrict__ bb1,
    const float* __restrict__ m1, const float* __restrict__ v1,
    const float* __restrict__ pw2, const float* __restrict__ aw1,
    const float* __restrict__ g2v, const float* __restrict__ bb2,
    const float* __restrict__ m2, const float* __restrict__ v2,
    const float* __restrict__ aw2, const float* __restrict__ ab1,
    float* __restrict__ fm_t, int* __restrict__ fpsi,
    float* __restrict__ w1f, float* __restrict__ b1f, float* __restrict__ ab1f,
    float* __restrict__ pw2t, float* __restrict__ aw1t,
    float* __restrict__ aw2t, float* __restrict__ W12t) {
  __shared__ __align__(16) char smem[53440];
  int blk = blockIdx.x;
  int tid = threadIdx.x;

  if (blk < 8) {
    // ---- FPS v6: 256 thr, 16 pts/thread. One LDS round-trip per step.
    float* lx = (float*)smem;
    float* ly = lx + NN;
    float* lz = ly + NN;
    int* fps_l = (int*)(lz + NN);
    ull* wkey = (ull*)(fps_l + MM);          // [2][4]
    float* wxyz = (float*)(wkey + 8);        // [2][4][4]
    int b = blk;
    const float* vb = verts + (size_t)b * 3 * NN;
    float px[16], py[16], pz[16], dist[16];
#pragma unroll
    for (int r = 0; r < 16; ++r) {
      int j = tid + r * 256;
      px[r] = vb[j]; py[r] = vb[NN + j]; pz[r] = vb[2 * NN + j];
      lx[j] = px[r]; ly[j] = py[r]; lz[j] = pz[r];
      dist[r] = 1e10f;
    }
    __syncthreads();
    float cx = lx[0], cy = ly[0], cz = lz[0];
    int far = 0;
    for (int s = 0; s < MM; ++s) {
      if (tid == 0) fps_l[s] = far;
      if (s == MM - 1) break;
      // dist update (reference-exact (p-c)^2 form) + per-lane argmax
      // (strict > keeps smallest r on ties -> smallest j within lane)
      float bestv = -1.0f;
      int bestr = 0;
#pragma unroll
      for (int r = 0; r < 16; ++r) {
        float dx = px[r] - cx, dy = py[r] - cy, dz = pz[r] - cz;
        float d = dx * dx + dy * dy + dz * dz;
        dist[r] = fminf(dist[r], d);
        if (dist[r] > bestv) { bestv = dist[r]; bestr = r; }
      }
      int bestj = tid + bestr * 256;
      // gather own candidate coords (latency hidden under DPP chain)
      float gx = lx[bestj], gy = ly[bestj], gz = lz[bestj];
      // paired u64 DPP max chain: key = (f32bits(bestv), 4095-bestj)
      unsigned khi = __float_as_uint(bestv);
      unsigned klo = 4095u - (unsigned)bestj;
#define PRED(CTRL)                                                            \
      {                                                                       \
        unsigned ohi = (unsigned)__builtin_amdgcn_update_dpp(                 \
            (int)khi, (int)khi, CTRL, 0xF, 0xF, false);                       \
        unsigned olo = (unsigned)__builtin_amdgcn_update_dpp(                 \
            (int)klo, (int)klo, CTRL, 0xF, 0xF, false);                       \
        bool t = (ohi > khi) || (ohi == khi && olo > klo);                    \
        khi = t ? ohi : khi;                                                  \
        klo = t ? olo : klo;                                                  \
      }
      PRED(0x111) PRED(0x112) PRED(0x114) PRED(0x118) PRED(0x142) PRED(0x143)
#undef PRED
      unsigned shi = (unsigned)__builtin_amdgcn_readlane((int)khi, 63);
      unsigned slo = (unsigned)__builtin_amdgcn_readlane((int)klo, 63);
      int wl = (4095 - (int)slo) & 63;  // winner lane (j%256==tid, &63=lane)
      float wx = __uint_as_float(
          (unsigned)__builtin_amdgcn_readlane(__float_as_int(gx), wl));
      float wy = __uint_as_float(
          (unsigned)__builtin_amdgcn_readlane(__float_as_int(gy), wl));
      float wz = __uint_as_float(
          (unsigned)__builtin_amdgcn_readlane(__float_as_int(gz), wl));
      int p = s & 1, w = tid >> 6;
      if ((tid & 63) == 0) {
        wkey[p * 4 + w] = ((ull)shi << 32) | (ull)slo;
        *(float4*)(wxyz + (p * 4 + w) * 4) = make_float4(wx, wy, wz, 0.f);
      }
      __syncthreads();
      ull k0 = wkey[p * 4 + 0], k1 = wkey[p * 4 + 1];
      ull k2 = wkey[p * 4 + 2], k3 = wkey[p * 4 + 3];
      float4 c0 = *(float4*)(wxyz + (p * 4 + 0) * 4);
      float4 c1 = *(float4*)(wxyz + (p * 4 + 1) * 4);
      float4 c2 = *(float4*)(wxyz + (p * 4 + 2) * 4);
      float4 c3 = *(float4*)(wxyz + (p * 4 + 3) * 4);
      if (k1 > k0) { k0 = k1; c0 = c1; }
      if (k3 > k2) { k2 = k3; c2 = c3; }
      if (k2 > k0) { k0 = k2; c0 = c2; }
      far = 4095 - (int)(k0 & 0xFFFull);
      cx = c0.x; cy = c0.y; cz = c0.z;
    }
    __syncthreads();
    for (int x = tid; x < MM; x += 256) fpsi[b * MM + x] = fps_l[x];

  } else if (blk == 8) {
    // ---- small weight prep (BN folds + transposes)
    if (tid < 64) {
      float s = g1[tid] * rsqrtf(v1[tid] + 1e-5f);
      w1f[tid * 4 + 0] = pw1[tid * 3 + 0] * s;
      w1f[tid * 4 + 1] = pw1[tid * 3 + 1] * s;
      w1f[tid * 4 + 2] = pw1[tid * 3 + 2] * s;
      w1f[tid * 4 + 3] = 0.f;
      b1f[tid] = (pb1[tid] - m1[tid]) * s + bb1[tid];
      float s2 = g2v[tid] * rsqrtf(v2[tid] + 1e-5f);
      ab1f[tid] = (ab1[tid] - m2[tid]) * s2 + bb2[tid];
    }
    for (int x = tid; x < 64 * 256; x += 256) {
      int i = x >> 8, c = x & 255;
      pw2t[x] = pw2[c * 64 + i];
    }
    for (int x = tid; x < 256 * 64; x += 256) {
      int c = x >> 6, d = x & 63;
      float s2 = g2v[d] * rsqrtf(v2[d] + 1e-5f);
      aw1t[x] = aw1[d * 256 + c] * s2;
    }
    for (int x = tid; x < 64 * OC; x += 256) {
      int i = x / OC, o = x % OC;
      aw2t[i * 260 + o] = aw2[o * 64 + i];
    }

  } else if (blk < 25) {
    // ---- W12t[i][d] = sum_c pw2[c][i]*aw1[d][c]*s2[d]
    int i = tid & 63;
    int d = (blk - 9) * 4 + (tid >> 6);
    float s2 = g2v[d] * rsqrtf(v2[d] + 1e-5f);
    const float* arow = aw1 + d * 256;
    float s = 0.f;
#pragma unroll 4
    for (int c = 0; c < 256; ++c) s += pw2[c * 64 + i] * arow[c];
    W12t[i * 64 + d] = s * s2;

  } else {
    // ---- transpose feature_map (B,C,N) -> (B,N,C)
    float (*tile)[65] = (float(*)[65])smem;
    int rb = blk - 25;
    int b = rb >> 8;
    int rem = rb & 255;
    int c0 = (rem >> 6) * 64;
    int n0 = (rem & 63) * 64;
    const float* src = fm + (size_t)b * CC * NN;
    float* dst = fm_t + (size_t)b * NN * CC;
    int tx = tid & 63, ty = tid >> 6;
    for (int r = ty; r < 64; r += 4)
      tile[r][tx] = src[(size_t)(c0 + r) * NN + n0 + tx];
    __syncthreads();
    for (int r = ty; r < 64; r += 4)
      dst[(size_t)(n0 + r) * CC + c0 + tx] = tile[tx][r];
  }
}

// ---------------------------------------------------------------------------
// PHASE 2: blocks 0-511 G2 GEMM tiles | 512-2559 KNN (4 waves/block, one
// key point per wave). Both depend only on phase1 outputs.
__global__ __launch_bounds__(256) void phase2(
    const float* __restrict__ verts, const float* __restrict__ fm,
    const float* __restrict__ aw1t, const int* __restrict__ fpsi,
    int* __restrict__ knni, float* __restrict__ G2) {
  __shared__ __align__(16) char smem[66560];
  int blk = blockIdx.x;
  int tid = threadIdx.x;

  if (blk < 512) {
    // ---- G2[b][n][d] = sum_c aw1t[c][d] * fm[b][c][n]
    float (*a_l)[68] = (float(*)[68])smem;
    float (*b_l)[68] = (float(*)[68])(smem + 64 * 68 * 4);
    int b = blk >> 6;
    int n0 = (blk & 63) * 64;
    int rr = tid >> 4, q4 = tid & 15;
    float acc[4][4];
#pragma unroll
    for (int q = 0; q < 4; ++q)
#pragma unroll
      for (int x = 0; x < 4; ++x) acc[q][x] = 0.f;
    for (int c0 = 0; c0 < 256; c0 += 64) {
      __syncthreads();
#pragma unroll
      for (int rep = 0; rep < 4; ++rep) {
        int cc = rr + rep * 16;
        *(float4*)&a_l[cc][q4 * 4] =
            *(const float4*)&fm[((size_t)b * CC + c0 + cc) * NN + n0 + q4 * 4];
        *(float4*)&b_l[cc][q4 * 4] = *(const float4*)&aw1t[(c0 + cc) * 64 + q4 * 4];
      }
      __syncthreads();
#pragma unroll 8
      for (int kk = 0; kk < 64; ++kk) {
        float4 a4 = *(const float4*)&a_l[kk][rr * 4];
        float4 b4 = *(const float4*)&b_l[kk][q4 * 4];
        float av[4] = {a4.x, a4.y, a4.z, a4.w};
#pragma unroll
        for (int q = 0; q < 4; ++q) {
          acc[q][0] += av[q] * b4.x;
          acc[q][1] += av[q] * b4.y;
          acc[q][2] += av[q] * b4.z;
          acc[q][3] += av[q] * b4.w;
        }
      }
    }
#pragma unroll
    for (int q = 0; q < 4; ++q)
      *(float4*)&G2[((size_t)b * NN + n0 + rr * 4 + q) * 64 + q4 * 4] =
          make_float4(acc[q][0], acc[q][1], acc[q][2], acc[q][3]);

  } else {
    // ---- KNN top-16, one wave per key point
    int wave = tid >> 6, lane = tid & 63;
    int bm = (blk - 512) * 4 + wave;
    int b = bm >> 10, m = bm & 1023;
    float* dbuf = (float*)smem + wave * (64 * 65);
    const float* vb = verts + (size_t)b * 3 * NN;
    int jm = fpsi[b * MM + m];
    float kx = vb[jm], ky = vb[NN + jm], kz = vb[2 * NN + jm];
    float kn = kx * kx + ky * ky + kz * kz;
    float v1 = INFINITY, v2 = INFINITY;
    int i1 = -1, i2 = -1;
    for (int t = 0; t < 64; ++t) {
      int j = t * 64 + lane;
      float x = vb[j], y = vb[NN + j], z = vb[2 * NN + j];
      float xn = x * x + y * y + z * z;
      float d = kn + xn - 2.0f * (kx * x + ky * y + kz * z);
      dbuf[lane * 65 + t] = d;
      if (d < v1) { v2 = v1; i2 = i1; v1 = d; i1 = j; }
      else if (d < v2) { v2 = d; i2 = j; }
    }
    for (int it = 0; it < KNB; ++it) {
      float rv = v1;
      int ri = i1;
#pragma unroll
      for (int off = 32; off >= 1; off >>= 1) {
        float ov = __shfl_down(rv, off, 64);
        int oi = __shfl_down(ri, off, 64);
        if (ov < rv || (ov == rv && oi < ri)) { rv = ov; ri = oi; }
      }
      ri = __shfl(ri, 0, 64);
      if (lane == 0) knni[(size_t)(b * MM + m) * KNB + it] = ri;
      if (i1 == ri) {
        dbuf[lane * 65 + (ri >> 6)] = INFINITY;
        v1 = v2; i1 = i2;
        v2 = INFINITY; i2 = -1;
        if (i1 < 0) {
          v1 = INFINITY; v2 = INFINITY; i1 = -1; i2 = -1;
          for (int t = 0; t < 64; ++t) {
            float d = dbuf[lane * 65 + t];
            int j = t * 64 + lane;
            if (d < v1) { v2 = v1; i2 = i1; v1 = d; i1 = j; }
            else if (d < v2) { v2 = d; i2 = j; }
          }
        }
      }
    }
  }
}

// ---------------------------------------------------------------------------
// Fused per-(b,m). Register-frugal stage D (max 16-float arrays). Unchanged.
__global__ __launch_bounds__(256, 3) void fuse_kernel(
    const float* __restrict__ verts, const float* __restrict__ fm_t,
    const float* __restrict__ G2,
    const int* __restrict__ fpsi, const int* __restrict__ knni,
    const float* __restrict__ w1f, const float* __restrict__ b1f,
    const float* __restrict__ ab1f, const float* __restrict__ aw1t,
    const float* __restrict__ W12t, const float* __restrict__ pw2t,
    const float* __restrict__ pb2, const float* __restrict__ aw2t,
    const float* __restrict__ ab2, float* __restrict__ out) {
  int bm = blockIdx.x;
  int b = bm & 7, m = bm >> 3;  // batch -> XCD pinning
  int tid = threadIdx.x;

  __shared__ __attribute__((aligned(16))) float kfpb[256];
  __shared__ __attribute__((aligned(16))) float pb2_l[256];
  __shared__ __attribute__((aligned(16))) float gp[3][16];
  __shared__ __attribute__((aligned(16))) float kp[4];
  __shared__ int kidx[16];
  __shared__ __attribute__((aligned(16))) float W12_l[64][68];
  __shared__ __attribute__((aligned(16))) float h_l[16][68];
  __shared__ __attribute__((aligned(16))) float hT_l[64][20];
  __shared__ __attribute__((aligned(16))) float h2T_l[64][20];
  __shared__ __attribute__((aligned(16))) float vmp[4][64];
  __shared__ __attribute__((aligned(16))) float vm_l[64];

  const float* vb = verts + (size_t)b * 3 * NN;
  const float* fb = fm_t + (size_t)b * NN * CC;
  int jm = fpsi[b * MM + m];
  if (tid < 16) kidx[tid] = knni[((size_t)b * MM + m) * 16 + tid];
  kfpb[tid] = fb[(size_t)jm * CC + tid] + pb2[tid];
  pb2_l[tid] = pb2[tid];
  if (tid < 3) kp[tid] = vb[tid * NN + jm];
  __syncthreads();

  if (tid < 48) {
    int c = tid >> 4, k = tid & 15;
    gp[c][k] = vb[c * NN + kidx[k]];
  }
  {
    int i = tid >> 4, d4 = tid & 15;
#pragma unroll
    for (int rep = 0; rep < 4; ++rep)
      *(float4*)&W12_l[i + rep * 16][d4 * 4] =
          *(const float4*)&W12t[(i + rep * 16) * 64 + d4 * 4];
  }
  {
    int d = tid & 63, part = tid >> 6;
    float acc = 0.f;
#pragma unroll 4
    for (int cc = 0; cc < 64; ++cc) {
      int c = part * 64 + cc;
      acc += aw1t[c * 64 + d] * kfpb[c];
    }
    vmp[part][d] = acc;
  }
  __syncthreads();
  if (tid < 64)
    vm_l[tid] = vmp[0][tid] + vmp[1][tid] + vmp[2][tid] + vmp[3][tid] + ab1f[tid];

  {
    int d = tid & 63, part = tid >> 6;
    float wd0 = w1f[d * 4 + 0], wd1 = w1f[d * 4 + 1], wd2 = w1f[d * 4 + 2];
    float bd = b1f[d];
#pragma unroll
    for (int j = 0; j < 4; ++j) {
      int k = part * 4 + j;
      float hv = wd0 * (kp[0] - gp[0][k]) + wd1 * (kp[1] - gp[1][k]) +
                 wd2 * (kp[2] - gp[2][k]) + bd;
      hv = (hv > 0.f) ? hv : 0.2f * hv;
      h_l[k][d] = hv;
      hT_l[d][k] = hv;
    }
  }
  __syncthreads();

  {
    int k = tid & 15, d2 = tid >> 4;
    float4 g4 = *(const float4*)&G2[((size_t)b * NN + kidx[k]) * 64 + d2 * 4];
    float a0 = 0.f, a1 = 0.f, a2 = 0.f, a3 = 0.f;
#pragma unroll 4
    for (int i = 0; i < 64; ++i) {
      float hv = h_l[k][i];
      float4 w4 = *(const float4*)&W12_l[i][d2 * 4];
      a0 += hv * w4.x; a1 += hv * w4.y; a2 += hv * w4.z; a3 += hv * w4.w;
    }
    float4 v4 = *(const float4*)&vm_l[d2 * 4];
    float r0 = v4.x - g4.x + a0;
    float r1 = v4.y - g4.y + a1;
    float r2 = v4.z - g4.z + a2;
    float r3 = v4.w - g4.w + a3;
    h2T_l[d2 * 4 + 0][k] = (r0 > 0.f) ? r0 : 0.2f * r0;
    h2T_l[d2 * 4 + 1][k] = (r1 > 0.f) ? r1 : 0.2f * r1;
    h2T_l[d2 * 4 + 2][k] = (r2 > 0.f) ? r2 : 0.2f * r2;
    h2T_l[d2 * 4 + 3][k] = (r3 > 0.f) ? r3 : 0.2f * r3;
  }
  __syncthreads();

  if (tid < 3) {
    float lg[16];
    float bias = ab2[tid];
#pragma unroll
    for (int k = 0; k < 16; ++k) lg[k] = bias;
    const float* wp = aw2t + tid;
    for (int i = 0; i < 64; ++i) {
      float wv = wp[i * 260];
      float4 ha = *(const float4*)&h2T_l[i][0];
      float4 hb = *(const float4*)&h2T_l[i][4];
      float4 hc = *(const float4*)&h2T_l[i][8];
      float4 hd = *(const float4*)&h2T_l[i][12];
      lg[0] += wv * ha.x;  lg[1] += wv * ha.y;  lg[2] += wv * ha.z;  lg[3] += wv * ha.w;
      lg[4] += wv * hb.x;  lg[5] += wv * hb.y;  lg[6] += wv * hb.z;  lg[7] += wv * hb.w;
      lg[8] += wv * hc.x;  lg[9] += wv * hc.y;  lg[10] += wv * hc.z; lg[11] += wv * hc.w;
      lg[12] += wv * hd.x; lg[13] += wv * hd.y; lg[14] += wv * hd.z; lg[15] += wv * hd.w;
    }
    float mx = lg[0];
#pragma unroll
    for (int k = 1; k < 16; ++k) mx = fmaxf(mx, lg[k]);
    float sum = 0.f;
#pragma unroll
    for (int k = 0; k < 16; ++k) { lg[k] = __expf(lg[k] - mx); sum += lg[k]; }
    float inv = 1.f / sum;
    float a2 = 0.f;
#pragma unroll
    for (int k = 0; k < 16; ++k) a2 += lg[k] * gp[tid][k];
    out[((size_t)b * OC + tid) * MM + m] = a2 * inv;
  }

  {
    int o = tid + 3;
    float gfv[16];
#pragma unroll
    for (int k = 0; k < 16; ++k)
      gfv[k] = fb[(size_t)kidx[k] * CC + tid];
    float lg[16];
    float bias = ab2[o];
#pragma unroll
    for (int k = 0; k < 16; ++k) lg[k] = bias;
    const float* wp = aw2t + o;
#pragma unroll 4
    for (int i = 0; i < 64; ++i) {
      float wv = wp[i * 260];
      float4 ha = *(const float4*)&h2T_l[i][0];
      float4 hb = *(const float4*)&h2T_l[i][4];
      float4 hc = *(const float4*)&h2T_l[i][8];
      float4 hd = *(const float4*)&h2T_l[i][12];
      lg[0] += wv * ha.x;  lg[1] += wv * ha.y;  lg[2] += wv * ha.z;  lg[3] += wv * ha.w;
      lg[4] += wv * hb.x;  lg[5] += wv * hb.y;  lg[6] += wv * hb.z;  lg[7] += wv * hb.w;
      lg[8] += wv * hc.x;  lg[9] += wv * hc.y;  lg[10] += wv * hc.z; lg[11] += wv * hc.w;
      lg[12] += wv * hd.x; lg[13] += wv * hd.y; lg[14] += wv * hd.z; lg[15] += wv * hd.w;
    }
    float mx = lg[0];
#pragma unroll
    for (int k = 1; k < 16; ++k) mx = fmaxf(mx, lg[k]);
    float sum = 0.f;
#pragma unroll
    for (int k = 0; k < 16; ++k) { lg[k] = __expf(lg[k] - mx); sum += lg[k]; }
    float inv = 1.f / sum;
#pragma unroll
    for (int k = 0; k < 16; ++k) lg[k] *= inv;
    float acc = 0.f;
#pragma unroll
    for (int k = 0; k < 16; ++k) acc += lg[k] * gfv[k];
    const float* pcol = pw2t + tid;
#pragma unroll 4
    for (int i = 0; i < 64; ++i) {
      float p = pcol[i * 256];
      float4 ha = *(const float4*)&hT_l[i][0];
      float4 hb = *(const float4*)&hT_l[i][4];
      float4 hc = *(const float4*)&hT_l[i][8];
      float4 hd = *(const float4*)&hT_l[i][12];
      float hw = lg[0] * ha.x + lg[1] * ha.y + lg[2] * ha.z + lg[3] * ha.w +
                 lg[4] * hb.x + lg[5] * hb.y + lg[6] * hb.z + lg[7] * hb.w +
                 lg[8] * hc.x + lg[9] * hc.y + lg[10] * hc.z + lg[11] * hc.w +
                 lg[12] * hd.x + lg[13] * hd.y + lg[14] * hd.z + lg[15] * hd.w;
      acc += p * hw;
    }
    out[((size_t)b * OC + o) * MM + m] = pb2_l[tid] + acc;
  }
}

// ---------------------------------------------------------------------------
extern "C" void kernel_launch(void* const* d_in, const int* in_sizes, int n_in,
                              void* d_out, int out_size, void* d_ws, size_t ws_size,
                              hipStream_t stream) {
  (void)in_sizes; (void)n_in; (void)out_size; (void)ws_size;
  const float* verts = (const float*)d_in[0];
  const float* fm = (const float*)d_in[1];
  const float* pw1 = (const float*)d_in[2];
  const float* pb1 = (const float*)d_in[3];
  const float* g1 = (const float*)d_in[4];
  const float* bb1 = (const float*)d_in[5];
  const float* m1 = (const float*)d_in[6];
  const float* v1 = (const float*)d_in[7];
  const float* pw2 = (const float*)d_in[8];
  const float* pb2 = (const float*)d_in[9];
  const float* aw1 = (const float*)d_in[10];
  const float* ab1 = (const float*)d_in[11];
  const float* g2 = (const float*)d_in[12];
  const float* bb2 = (const float*)d_in[13];
  const float* m2 = (const float*)d_in[14];
  const float* v2 = (const float*)d_in[15];
  const float* aw2 = (const float*)d_in[16];
  const float* ab2 = (const float*)d_in[17];
  float* out = (float*)d_out;

  char* ws = (char*)d_ws;
  float* fm_t = (float*)ws;                               // 33,554,432 B
  float* G2 = (float*)(ws + 33554432);                    //  8,388,608 B
  int* fpsi = (int*)(ws + 41943040);                      //     32,768 B
  int* knni = (int*)(ws + 41975808);                      //    524,288 B
  float* w1f = (float*)(ws + 42500096);
  float* b1f = w1f + 256;
  float* ab1f = b1f + 64;
  float* pw2t = ab1f + 64;
  float* aw1t = pw2t + 64 * 256;
  float* aw2t = aw1t + 256 * 64;
  float* W12t = aw2t + 64 * 260;

  hipLaunchKernelGGL(phase1, dim3(2073), dim3(256), 0, stream,
                     verts, fm, pw1, pb1, g1, bb1, m1, v1, pw2, aw1, g2, bb2,
                     m2, v2, aw2, ab1,
                     fm_t, fpsi, w1f, b1f, ab1f, pw2t, aw1t, aw2t, W12t);
  hipLaunchKernelGGL(phase2, dim3(2560), dim3(256), 0, stream,
                     verts, fm, aw1t, fpsi, knni, G2);
  hipLaunchKernelGGL(fuse_kernel, dim3(8192), dim3(256), 0, stream,
                     verts, fm_t, G2, fpsi, knni, w1f, b1f, ab1f, aw1t, W12t,
                     pw2t, pb2, aw2t, ab2, out);
}

// Round 8
// 1171.640 us; speedup vs baseline: 1.1172x; 1.1172x over previous
//
#include <hip/hip_runtime.h>
#include <math.h>

#define BB 8
#define NN 4096
#define CC 256
#define DD 64
#define MM 1024
#define KNB 16
#define OC 259

typedef unsigned long long ull;

// ---------------------------------------------------------------------------
// PHASE 1: blk 0-7 FPS | 8-519 G2 GEMM (self-scaled aw1, no prep dep) |
// 520 prep | 521-536 W12 | 537-2584 transpose. fps dominates (~680us); all
// other roles (~70us of work) run concurrently on the remaining CUs.
__global__ __launch_bounds__(256) void phase1(
    const float* __restrict__ verts, const float* __restrict__ fm,
    const float* __restrict__ pw1, const float* __restrict__ pb1,
    const float* __restrict__ g1, const float* __restrict__ bb1,
    const float* __restrict__ m1, const float* __restrict__ v1,
    const float* __restrict__ pw2, const float* __restrict__ aw1,
    const float* __restrict__ g2v, const float* __restrict__ bb2,
    const float* __restrict__ m2, const float* __restrict__ v2,
    const float* __restrict__ aw2, const float* __restrict__ ab1,
    float* __restrict__ fm_t, int* __restrict__ fpsi, float* __restrict__ G2,
    float* __restrict__ w1f, float* __restrict__ b1f, float* __restrict__ ab1f,
    float* __restrict__ pw2t, float* __restrict__ aw1t,
    float* __restrict__ aw2t, float* __restrict__ W12t) {
  __shared__ __align__(16) char smem[53440];
  int blk = blockIdx.x;
  int tid = threadIdx.x;

  if (blk < 8) {
    // ---- FPS v5 (verbatim from the 675us round-6 kernel): 256 thr,
    // 16 pts/thread, reference-exact (p-c)^2 dist, two-pass DPP reduce,
    // u64 parity slots, depth-2 tree, no global stores in the loop.
    float* lx = (float*)smem;
    float* ly = lx + NN;
    float* lz = ly + NN;
    int* fps_l = (int*)(lz + NN);
    ull* wres = (ull*)(fps_l + MM);  // [2][4]
    int b = blk;
    const float* vb = verts + (size_t)b * 3 * NN;
    float px[16], py[16], pz[16], dist[16];
#pragma unroll
    for (int r = 0; r < 16; ++r) {
      int j = tid + r * 256;
      px[r] = vb[j]; py[r] = vb[NN + j]; pz[r] = vb[2 * NN + j];
      lx[j] = px[r]; ly[j] = py[r]; lz[j] = pz[r];
      dist[r] = 1e10f;
    }
    __syncthreads();
    int far = 0;
    for (int s = 0; s < MM; ++s) {
      if (tid == 0) fps_l[s] = far;
      if (s == MM - 1) break;
      float cx = lx[far], cy = ly[far], cz = lz[far];
      float vmax = -1.0f;
#pragma unroll
      for (int r = 0; r < 16; ++r) {
        float dx = px[r] - cx, dy = py[r] - cy, dz = pz[r] - cz;
        float d = dx * dx + dy * dy + dz * dz;
        dist[r] = fminf(dist[r], d);
        vmax = fmaxf(vmax, dist[r]);
      }
#define VRED(CTRL)                                                            \
      {                                                                       \
        int o = __builtin_amdgcn_update_dpp(__float_as_int(vmax),             \
                                            __float_as_int(vmax), CTRL, 0xF,  \
                                            0xF, false);                      \
        vmax = fmaxf(vmax, __int_as_float(o));                                \
      }
      VRED(0x111) VRED(0x112) VRED(0x114) VRED(0x118) VRED(0x142) VRED(0x143)
#undef VRED
      float svmax =
          __int_as_float(__builtin_amdgcn_readlane(__float_as_int(vmax), 63));
      int minj = 0x7FFFFFFF;
#pragma unroll
      for (int r = 0; r < 16; ++r) {
        int cand = (dist[r] == svmax) ? (tid + r * 256) : 0x7FFFFFFF;
        minj = (cand < minj) ? cand : minj;
      }
#define IRED(CTRL)                                                            \
      {                                                                       \
        int o = __builtin_amdgcn_update_dpp(minj, minj, CTRL, 0xF, 0xF,       \
                                            false);                          \
        minj = (o < minj) ? o : minj;                                         \
      }
      IRED(0x111) IRED(0x112) IRED(0x114) IRED(0x118) IRED(0x142) IRED(0x143)
#undef IRED
      if ((tid & 63) == 63)
        wres[(s & 1) * 4 + (tid >> 6)] =
            ((ull)(unsigned)__float_as_int(svmax) << 12) |
            (ull)(4095 - minj);
      __syncthreads();
      int p = s & 1;
      ull k0 = wres[p * 4 + 0], k1 = wres[p * 4 + 1];
      ull k2 = wres[p * 4 + 2], k3 = wres[p * 4 + 3];
      ull a = (k0 > k1) ? k0 : k1;
      ull c = (k2 > k3) ? k2 : k3;
      a = (c > a) ? c : a;
      far = 4095 - (int)(a & 0xFFFull);
    }
    __syncthreads();
    for (int x = tid; x < MM; x += 256) fpsi[b * MM + x] = fps_l[x];

  } else if (blk < 520) {
    // ---- G2[b][n][d] = sum_c (aw1[d][c]*s2[d]) * fm[b][c][n]
    // s2 applied on the fly (same expression as prep -> bitwise-identical
    // to the aw1t path); no dependency on the prep block.
    float (*a_l)[68] = (float(*)[68])smem;
    float (*b_l)[68] = (float(*)[68])(smem + 64 * 68 * 4);
    int t = blk - 8;
    int b = t >> 6;
    int n0 = (t & 63) * 64;
    int rr = tid >> 4, q4 = tid & 15;
    float s2v[4];
#pragma unroll
    for (int j = 0; j < 4; ++j)
      s2v[j] = g2v[q4 * 4 + j] * rsqrtf(v2[q4 * 4 + j] + 1e-5f);
    float acc[4][4];
#pragma unroll
    for (int q = 0; q < 4; ++q)
#pragma unroll
      for (int x = 0; x < 4; ++x) acc[q][x] = 0.f;
    for (int c0 = 0; c0 < 256; c0 += 64) {
      __syncthreads();
#pragma unroll
      for (int rep = 0; rep < 4; ++rep) {
        int cc = rr + rep * 16;
        *(float4*)&a_l[cc][q4 * 4] =
            *(const float4*)&fm[((size_t)b * CC + c0 + cc) * NN + n0 + q4 * 4];
        float bv[4];
#pragma unroll
        for (int j = 0; j < 4; ++j)
          bv[j] = aw1[(q4 * 4 + j) * 256 + c0 + cc] * s2v[j];
        *(float4*)&b_l[cc][q4 * 4] = make_float4(bv[0], bv[1], bv[2], bv[3]);
      }
      __syncthreads();
#pragma unroll 8
      for (int kk = 0; kk < 64; ++kk) {
        float4 a4 = *(const float4*)&a_l[kk][rr * 4];
        float4 b4 = *(const float4*)&b_l[kk][q4 * 4];
        float av[4] = {a4.x, a4.y, a4.z, a4.w};
#pragma unroll
        for (int q = 0; q < 4; ++q) {
          acc[q][0] += av[q] * b4.x;
          acc[q][1] += av[q] * b4.y;
          acc[q][2] += av[q] * b4.z;
          acc[q][3] += av[q] * b4.w;
        }
      }
    }
#pragma unroll
    for (int q = 0; q < 4; ++q)
      *(float4*)&G2[((size_t)b * NN + n0 + rr * 4 + q) * 64 + q4 * 4] =
          make_float4(acc[q][0], acc[q][1], acc[q][2], acc[q][3]);

  } else if (blk == 520) {
    // ---- small weight prep (BN folds + transposes)
    if (tid < 64) {
      float s = g1[tid] * rsqrtf(v1[tid] + 1e-5f);
      w1f[tid * 4 + 0] = pw1[tid * 3 + 0] * s;
      w1f[tid * 4 + 1] = pw1[tid * 3 + 1] * s;
      w1f[tid * 4 + 2] = pw1[tid * 3 + 2] * s;
      w1f[tid * 4 + 3] = 0.f;
      b1f[tid] = (pb1[tid] - m1[tid]) * s + bb1[tid];
      float s2 = g2v[tid] * rsqrtf(v2[tid] + 1e-5f);
      ab1f[tid] = (ab1[tid] - m2[tid]) * s2 + bb2[tid];
    }
    for (int x = tid; x < 64 * 256; x += 256) {
      int i = x >> 8, c = x & 255;
      pw2t[x] = pw2[c * 64 + i];
    }
    for (int x = tid; x < 256 * 64; x += 256) {
      int c = x >> 6, d = x & 63;
      float s2 = g2v[d] * rsqrtf(v2[d] + 1e-5f);
      aw1t[x] = aw1[d * 256 + c] * s2;
    }
    for (int x = tid; x < 64 * OC; x += 256) {
      int i = x / OC, o = x % OC;
      aw2t[i * 260 + o] = aw2[o * 64 + i];
    }

  } else if (blk < 537) {
    // ---- W12t[i][d] = sum_c pw2[c][i]*aw1[d][c]*s2[d]
    int i = tid & 63;
    int d = (blk - 521) * 4 + (tid >> 6);
    float s2 = g2v[d] * rsqrtf(v2[d] + 1e-5f);
    const float* arow = aw1 + d * 256;
    float s = 0.f;
#pragma unroll 4
    for (int c = 0; c < 256; ++c) s += pw2[c * 64 + i] * arow[c];
    W12t[i * 64 + d] = s * s2;

  } else {
    // ---- transpose feature_map (B,C,N) -> (B,N,C)
    float (*tile)[65] = (float(*)[65])smem;
    int rb = blk - 537;
    int b = rb >> 8;
    int rem = rb & 255;
    int c0 = (rem >> 6) * 64;
    int n0 = (rem & 63) * 64;
    const float* src = fm + (size_t)b * CC * NN;
    float* dst = fm_t + (size_t)b * NN * CC;
    int tx = tid & 63, ty = tid >> 6;
    for (int r = ty; r < 64; r += 4)
      tile[r][tx] = src[(size_t)(c0 + r) * NN + n0 + tx];
    __syncthreads();
    for (int r = ty; r < 64; r += 4)
      dst[(size_t)(n0 + r) * CC + c0 + tx] = tile[tx][r];
  }
}

// ---------------------------------------------------------------------------
// PHASE 2: KNN only — 2048 blocks x 4 waves, one key point per wave.
__global__ __launch_bounds__(256) void phase2(
    const float* __restrict__ verts, const int* __restrict__ fpsi,
    int* __restrict__ knni) {
  __shared__ __align__(16) char smem[66560];
  int blk = blockIdx.x;
  int tid = threadIdx.x;
  int wave = tid >> 6, lane = tid & 63;
  int bm = blk * 4 + wave;
  int b = bm >> 10, m = bm & 1023;
  float* dbuf = (float*)smem + wave * (64 * 65);
  const float* vb = verts + (size_t)b * 3 * NN;
  int jm = fpsi[b * MM + m];
  float kx = vb[jm], ky = vb[NN + jm], kz = vb[2 * NN + jm];
  float kn = kx * kx + ky * ky + kz * kz;
  float v1 = INFINITY, v2 = INFINITY;
  int i1 = -1, i2 = -1;
  for (int t = 0; t < 64; ++t) {
    int j = t * 64 + lane;
    float x = vb[j], y = vb[NN + j], z = vb[2 * NN + j];
    float xn = x * x + y * y + z * z;
    float d = kn + xn - 2.0f * (kx * x + ky * y + kz * z);
    dbuf[lane * 65 + t] = d;
    if (d < v1) { v2 = v1; i2 = i1; v1 = d; i1 = j; }
    else if (d < v2) { v2 = d; i2 = j; }
  }
  for (int it = 0; it < KNB; ++it) {
    float rv = v1;
    int ri = i1;
#pragma unroll
    for (int off = 32; off >= 1; off >>= 1) {
      float ov = __shfl_down(rv, off, 64);
      int oi = __shfl_down(ri, off, 64);
      if (ov < rv || (ov == rv && oi < ri)) { rv = ov; ri = oi; }
    }
    ri = __shfl(ri, 0, 64);
    if (lane == 0) knni[(size_t)(b * MM + m) * KNB + it] = ri;
    if (i1 == ri) {
      dbuf[lane * 65 + (ri >> 6)] = INFINITY;
      v1 = v2; i1 = i2;
      v2 = INFINITY; i2 = -1;
      if (i1 < 0) {
        v1 = INFINITY; v2 = INFINITY; i1 = -1; i2 = -1;
        for (int t = 0; t < 64; ++t) {
          float d = dbuf[lane * 65 + t];
          int j = t * 64 + lane;
          if (d < v1) { v2 = v1; i2 = i1; v1 = d; i1 = j; }
          else if (d < v2) { v2 = d; i2 = j; }
        }
      }
    }
  }
}

// ---------------------------------------------------------------------------
// Fused per-(b,m). Register-frugal stage D (max 16-float arrays). Unchanged.
__global__ __launch_bounds__(256, 3) void fuse_kernel(
    const float* __restrict__ verts, const float* __restrict__ fm_t,
    const float* __restrict__ G2,
    const int* __restrict__ fpsi, const int* __restrict__ knni,
    const float* __restrict__ w1f, const float* __restrict__ b1f,
    const float* __restrict__ ab1f, const float* __restrict__ aw1t,
    const float* __restrict__ W12t, const float* __restrict__ pw2t,
    const float* __restrict__ pb2, const float* __restrict__ aw2t,
    const float* __restrict__ ab2, float* __restrict__ out) {
  int bm = blockIdx.x;
  int b = bm & 7, m = bm >> 3;  // batch -> XCD pinning
  int tid = threadIdx.x;

  __shared__ __attribute__((aligned(16))) float kfpb[256];
  __shared__ __attribute__((aligned(16))) float pb2_l[256];
  __shared__ __attribute__((aligned(16))) float gp[3][16];
  __shared__ __attribute__((aligned(16))) float kp[4];
  __shared__ int kidx[16];
  __shared__ __attribute__((aligned(16))) float W12_l[64][68];
  __shared__ __attribute__((aligned(16))) float h_l[16][68];
  __shared__ __attribute__((aligned(16))) float hT_l[64][20];
  __shared__ __attribute__((aligned(16))) float h2T_l[64][20];
  __shared__ __attribute__((aligned(16))) float vmp[4][64];
  __shared__ __attribute__((aligned(16))) float vm_l[64];

  const float* vb = verts + (size_t)b * 3 * NN;
  const float* fb = fm_t + (size_t)b * NN * CC;
  int jm = fpsi[b * MM + m];
  if (tid < 16) kidx[tid] = knni[((size_t)b * MM + m) * 16 + tid];
  kfpb[tid] = fb[(size_t)jm * CC + tid] + pb2[tid];
  pb2_l[tid] = pb2[tid];
  if (tid < 3) kp[tid] = vb[tid * NN + jm];
  __syncthreads();

  if (tid < 48) {
    int c = tid >> 4, k = tid & 15;
    gp[c][k] = vb[c * NN + kidx[k]];
  }
  {
    int i = tid >> 4, d4 = tid & 15;
#pragma unroll
    for (int rep = 0; rep < 4; ++rep)
      *(float4*)&W12_l[i + rep * 16][d4 * 4] =
          *(const float4*)&W12t[(i + rep * 16) * 64 + d4 * 4];
  }
  {
    int d = tid & 63, part = tid >> 6;
    float acc = 0.f;
#pragma unroll 4
    for (int cc = 0; cc < 64; ++cc) {
      int c = part * 64 + cc;
      acc += aw1t[c * 64 + d] * kfpb[c];
    }
    vmp[part][d] = acc;
  }
  __syncthreads();
  if (tid < 64)
    vm_l[tid] = vmp[0][tid] + vmp[1][tid] + vmp[2][tid] + vmp[3][tid] + ab1f[tid];

  {
    int d = tid & 63, part = tid >> 6;
    float wd0 = w1f[d * 4 + 0], wd1 = w1f[d * 4 + 1], wd2 = w1f[d * 4 + 2];
    float bd = b1f[d];
#pragma unroll
    for (int j = 0; j < 4; ++j) {
      int k = part * 4 + j;
      float hv = wd0 * (kp[0] - gp[0][k]) + wd1 * (kp[1] - gp[1][k]) +
                 wd2 * (kp[2] - gp[2][k]) + bd;
      hv = (hv > 0.f) ? hv : 0.2f * hv;
      h_l[k][d] = hv;
      hT_l[d][k] = hv;
    }
  }
  __syncthreads();

  {
    int k = tid & 15, d2 = tid >> 4;
    float4 g4 = *(const float4*)&G2[((size_t)b * NN + kidx[k]) * 64 + d2 * 4];
    float a0 = 0.f, a1 = 0.f, a2 = 0.f, a3 = 0.f;
#pragma unroll 4
    for (int i = 0; i < 64; ++i) {
      float hv = h_l[k][i];
      float4 w4 = *(const float4*)&W12_l[i][d2 * 4];
      a0 += hv * w4.x; a1 += hv * w4.y; a2 += hv * w4.z; a3 += hv * w4.w;
    }
    float4 v4 = *(const float4*)&vm_l[d2 * 4];
    float r0 = v4.x - g4.x + a0;
    float r1 = v4.y - g4.y + a1;
    float r2 = v4.z - g4.z + a2;
    float r3 = v4.w - g4.w + a3;
    h2T_l[d2 * 4 + 0][k] = (r0 > 0.f) ? r0 : 0.2f * r0;
    h2T_l[d2 * 4 + 1][k] = (r1 > 0.f) ? r1 : 0.2f * r1;
    h2T_l[d2 * 4 + 2][k] = (r2 > 0.f) ? r2 : 0.2f * r2;
    h2T_l[d2 * 4 + 3][k] = (r3 > 0.f) ? r3 : 0.2f * r3;
  }
  __syncthreads();

  if (tid < 3) {
    float lg[16];
    float bias = ab2[tid];
#pragma unroll
    for (int k = 0; k < 16; ++k) lg[k] = bias;
    const float* wp = aw2t + tid;
    for (int i = 0; i < 64; ++i) {
      float wv = wp[i * 260];
      float4 ha = *(const float4*)&h2T_l[i][0];
      float4 hb = *(const float4*)&h2T_l[i][4];
      float4 hc = *(const float4*)&h2T_l[i][8];
      float4 hd = *(const float4*)&h2T_l[i][12];
      lg[0] += wv * ha.x;  lg[1] += wv * ha.y;  lg[2] += wv * ha.z;  lg[3] += wv * ha.w;
      lg[4] += wv * hb.x;  lg[5] += wv * hb.y;  lg[6] += wv * hb.z;  lg[7] += wv * hb.w;
      lg[8] += wv * hc.x;  lg[9] += wv * hc.y;  lg[10] += wv * hc.z; lg[11] += wv * hc.w;
      lg[12] += wv * hd.x; lg[13] += wv * hd.y; lg[14] += wv * hd.z; lg[15] += wv * hd.w;
    }
    float mx = lg[0];
#pragma unroll
    for (int k = 1; k < 16; ++k) mx = fmaxf(mx, lg[k]);
    float sum = 0.f;
#pragma unroll
    for (int k = 0; k < 16; ++k) { lg[k] = __expf(lg[k] - mx); sum += lg[k]; }
    float inv = 1.f / sum;
    float a2 = 0.f;
#pragma unroll
    for (int k = 0; k < 16; ++k) a2 += lg[k] * gp[tid][k];
    out[((size_t)b * OC + tid) * MM + m] = a2 * inv;
  }

  {
    int o = tid + 3;
    float gfv[16];
#pragma unroll
    for (int k = 0; k < 16; ++k)
      gfv[k] = fb[(size_t)kidx[k] * CC + tid];
    float lg[16];
    float bias = ab2[o];
#pragma unroll
    for (int k = 0; k < 16; ++k) lg[k] = bias;
    const float* wp = aw2t + o;
#pragma unroll 4
    for (int i = 0; i < 64; ++i) {
      float wv = wp[i * 260];
      float4 ha = *(const float4*)&h2T_l[i][0];
      float4 hb = *(const float4*)&h2T_l[i][4];
      float4 hc = *(const float4*)&h2T_l[i][8];
      float4 hd = *(const float4*)&h2T_l[i][12];
      lg[0] += wv * ha.x;  lg[1] += wv * ha.y;  lg[2] += wv * ha.z;  lg[3] += wv * ha.w;
      lg[4] += wv * hb.x;  lg[5] += wv * hb.y;  lg[6] += wv * hb.z;  lg[7] += wv * hb.w;
      lg[8] += wv * hc.x;  lg[9] += wv * hc.y;  lg[10] += wv * hc.z; lg[11] += wv * hc.w;
      lg[12] += wv * hd.x; lg[13] += wv * hd.y; lg[14] += wv * hd.z; lg[15] += wv * hd.w;
    }
    float mx = lg[0];
#pragma unroll
    for (int k = 1; k < 16; ++k) mx = fmaxf(mx, lg[k]);
    float sum = 0.f;
#pragma unroll
    for (int k = 0; k < 16; ++k) { lg[k] = __expf(lg[k] - mx); sum += lg[k]; }
    float inv = 1.f / sum;
#pragma unroll
    for (int k = 0; k < 16; ++k) lg[k] *= inv;
    float acc = 0.f;
#pragma unroll
    for (int k = 0; k < 16; ++k) acc += lg[k] * gfv[k];
    const float* pcol = pw2t + tid;
#pragma unroll 4
    for (int i = 0; i < 64; ++i) {
      float p = pcol[i * 256];
      float4 ha = *(const float4*)&hT_l[i][0];
      float4 hb = *(const float4*)&hT_l[i][4];
      float4 hc = *(const float4*)&hT_l[i][8];
      float4 hd = *(const float4*)&hT_l[i][12];
      float hw = lg[0] * ha.x + lg[1] * ha.y + lg[2] * ha.z + lg[3] * ha.w +
                 lg[4] * hb.x + lg[5] * hb.y + lg[6] * hb.z + lg[7] * hb.w +
                 lg[8] * hc.x + lg[9] * hc.y + lg[10] * hc.z + lg[11] * hc.w +
                 lg[12] * hd.x + lg[13] * hd.y + lg[14] * hd.z + lg[15] * hd.w;
      acc += p * hw;
    }
    out[((size_t)b * OC + o) * MM + m] = pb2_l[tid] + acc;
  }
}

// ---------------------------------------------------------------------------
extern "C" void kernel_launch(void* const* d_in, const int* in_sizes, int n_in,
                              void* d_out, int out_size, void* d_ws, size_t ws_size,
                              hipStream_t stream) {
  (void)in_sizes; (void)n_in; (void)out_size; (void)ws_size;
  const float* verts = (const float*)d_in[0];
  const float* fm = (const float*)d_in[1];
  const float* pw1 = (const float*)d_in[2];
  const float* pb1 = (const float*)d_in[3];
  const float* g1 = (const float*)d_in[4];
  const float* bb1 = (const float*)d_in[5];
  const float* m1 = (const float*)d_in[6];
  const float* v1 = (const float*)d_in[7];
  const float* pw2 = (const float*)d_in[8];
  const float* pb2 = (const float*)d_in[9];
  const float* aw1 = (const float*)d_in[10];
  const float* ab1 = (const float*)d_in[11];
  const float* g2 = (const float*)d_in[12];
  const float* bb2 = (const float*)d_in[13];
  const float* m2 = (const float*)d_in[14];
  const float* v2 = (const float*)d_in[15];
  const float* aw2 = (const float*)d_in[16];
  const float* ab2 = (const float*)d_in[17];
  float* out = (float*)d_out;

  char* ws = (char*)d_ws;
  float* fm_t = (float*)ws;                               // 33,554,432 B
  float* G2 = (float*)(ws + 33554432);                    //  8,388,608 B
  int* fpsi = (int*)(ws + 41943040);                      //     32,768 B
  int* knni = (int*)(ws + 41975808);                      //    524,288 B
  float* w1f = (float*)(ws + 42500096);
  float* b1f = w1f + 256;
  float* ab1f = b1f + 64;
  float* pw2t = ab1f + 64;
  float* aw1t = pw2t + 64 * 256;
  float* aw2t = aw1t + 256 * 64;
  float* W12t = aw2t + 64 * 260;

  hipLaunchKernelGGL(phase1, dim3(2585), dim3(256), 0, stream,
                     verts, fm, pw1, pb1, g1, bb1, m1, v1, pw2, aw1, g2, bb2,
                     m2, v2, aw2, ab1,
                     fm_t, fpsi, G2, w1f, b1f, ab1f, pw2t, aw1t, aw2t, W12t);
  hipLaunchKernelGGL(phase2, dim3(2048), dim3(256), 0, stream,
                     verts, fpsi, knni);
  hipLaunchKernelGGL(fuse_kernel, dim3(8192), dim3(256), 0, stream,
                     verts, fm_t, G2, fpsi, knni, w1f, b1f, ab1f, aw1t, W12t,
                     pw2t, pb2, aw2t, ab2, out);
}